// Round 5
// baseline (575.944 us; speedup 1.0000x reference)
//
#include <hip/hip_runtime.h>

// ---- problem constants (from reference) ----
#define SEQ      10688      // IMG_LEN + TEXT_LEN
#define IMG_LEN  10368      // 18*24*24
#define TEXT_LEN 320
#define DH       128
#define NHEADS   4
#define SLAB     3456       // 6*24*24 tokens per time-slab
#define KVC      64         // kv chunk rows
#define QT       128        // q rows per block (4 waves x 32)
#define NIT      81         // image q-tiles per head (IMG_LEN/128, 27 per slab: exact)
#define NTT      3          // text q-tiles per head (last tile half-valid)
// (1/sqrt(128)) * log2(e): scores in log2 domain -> exp2f softmax
#define SCALEL2E 0.12751744518924593f
#define DEFER_THR 8.0f      // defer-max rescale threshold (T13)

// split-K config
#define TSPLIT   4          // text: 167 chunks -> 42/42/42/41
#define ISPLIT   2          // image: 59 chunks -> 30/29
#define NTXTB    (NHEADS * NTT * TSPLIT)              // 48
#define NIMGB    (NHEADS * NIT * ISPLIT)              // 648
#define NPID     (NTXTB + NIMGB)                      // 696
#define WS_OP_FLOATS   ((size_t)NPID * QT * DH)
#define WS_ML_FLOATS   ((size_t)NPID * QT * 2)

typedef __bf16 bf16x8 __attribute__((ext_vector_type(8)));
typedef float  f32x4  __attribute__((ext_vector_type(4)));

__device__ __forceinline__ unsigned pk2bf(float a, float b) {
    union { __bf16 h[2]; unsigned u; } t;
    t.h[0] = (__bf16)a; t.h[1] = (__bf16)b;
    return t.u;
}

// NOTE: (256,2): (256,4) capped VGPR at 64 -> massive scratch spills (round 3).
template<bool SPLIT>
__global__ __launch_bounds__(256, 2) void sta_attn(const float* __restrict__ Qg,
                                                   const float* __restrict__ Kg,
                                                   const float* __restrict__ Vg,
                                                   float* __restrict__ Og,
                                                   float* __restrict__ Opart,
                                                   float* __restrict__ Ml) {
    // XOR-swizzled at 16B granule with row&7 key; no pads.
    __shared__ __align__(16) unsigned short LK[KVC * DH];     // K   [kv][d]   16KB
    __shared__ __align__(16) unsigned short VT[DH * KVC];     // V^T [d][kv]   16KB
    __shared__ __align__(16) unsigned short PL[4][32 * KVC];  // P   [q][kv] per wave 16KB

    const int tid  = threadIdx.x;
    const int lane = tid & 63;
    const int wv   = tid >> 6;
    const int q    = lane & 15;       // q-col within 16-wide MFMA tile
    const int g    = lane >> 4;       // lane group 0..3
    const int sw16 = (q & 7) << 4;    // 16B-granule swizzle key (bytes)

    int b = blockIdx.x;
    int head, qbase, nch, ch0, kvb0, pid = 0;
    bool isText;
    if constexpr (SPLIT) {
        if (b < NTXTB) {                       // text splits first (longest poles)
            int tb = b >> 2, s = b & 3;
            head = tb / NTT; qbase = IMG_LEN + (tb % NTT) * QT;
            isText = true; kvb0 = 0;
            ch0 = s * 42; nch = (s < 3) ? 42 : 41;
            pid = b;
        } else {
            int bb = b - NTXTB; int tile = bb >> 1, s = bb & 1;
            head = tile / NIT; qbase = (tile % NIT) * QT;
            isText = false; kvb0 = (qbase / SLAB) * SLAB;
            ch0 = s ? 30 : 0; nch = s ? 29 : 30;
            pid = NTXTB + bb;
        }
    } else {
        if (b < NHEADS * NTT) {
            head = b / NTT; qbase = IMG_LEN + (b % NTT) * QT;
            isText = true; ch0 = 0; nch = SEQ / KVC; kvb0 = 0;
        } else {
            int bb = b - NHEADS * NTT;
            head = bb / NIT; qbase = (bb % NIT) * QT;
            isText = false; ch0 = 0; nch = 54 + 5;
            kvb0 = (qbase / SLAB) * SLAB;
        }
    }

    const size_t hoff = (size_t)head * SEQ * DH;
    const float* Qh = Qg + hoff;
    const float* Kh = Kg + hoff;
    const float* Vh = Vg + hoff;

    // ---- Q fragments for 2 q-subtiles (B-operand layout), scale folded ----
    bf16x8 qf[2][4];
    #pragma unroll
    for (int n = 0; n < 2; ++n) {
        int qr = qbase + wv * 32 + n * 16 + q;
        if (qr > SEQ - 1) qr = SEQ - 1;            // text tile 2 tail: clamp (discarded at store)
        const float* qp = Qh + (size_t)qr * DH;
        #pragma unroll
        for (int c = 0; c < 4; ++c) {
            float4 a = *(const float4*)(qp + c * 32 + g * 8);
            float4 d = *(const float4*)(qp + c * 32 + g * 8 + 4);
            union { unsigned u[4]; bf16x8 v; } t;
            t.u[0] = pk2bf(a.x * SCALEL2E, a.y * SCALEL2E);
            t.u[1] = pk2bf(a.z * SCALEL2E, a.w * SCALEL2E);
            t.u[2] = pk2bf(d.x * SCALEL2E, d.y * SCALEL2E);
            t.u[3] = pk2bf(d.z * SCALEL2E, d.w * SCALEL2E);
            qf[n][c] = t.v;
        }
    }

    f32x4 o[2][8];
    #pragma unroll
    for (int n = 0; n < 2; ++n)
        #pragma unroll
        for (int dt = 0; dt < 8; ++dt) o[n][dt] = f32x4{0.f, 0.f, 0.f, 0.f};
    float mrun[2] = {-INFINITY, -INFINITY};
    float lsum[2] = {0.f, 0.f};

    float4 kreg[8];
    float  vreg[4][8];

    auto kvaddr = [&](int gch) -> int {
        return isText ? gch * KVC
                      : (gch < 54 ? kvb0 + gch * KVC : IMG_LEN + (gch - 54) * KVC);
    };

    #define ISSUE(KVBASE)                                                        \
        {   const int _kb = (KVBASE);                                            \
            _Pragma("unroll")                                                    \
            for (int s = 0; s < 8; ++s) {                                        \
                int idx = tid + (s << 8);                                        \
                int kv = idx >> 5, dq = idx & 31;                                \
                kreg[s] = *(const float4*)(Kh + (size_t)(_kb + kv) * DH + dq*4); \
            }                                                                    \
            _Pragma("unroll")                                                    \
            for (int t = 0; t < 4; ++t) {                                        \
                int idx = tid + (t << 8);                                        \
                int d = idx & 127, kvb = idx >> 7;                               \
                const float* vp = Vh + (size_t)(_kb + kvb * 8) * DH + d;         \
                _Pragma("unroll")                                                \
                for (int j = 0; j < 8; ++j) vreg[t][j] = vp[j * DH];             \
            }                                                                    \
        }

    #define WRITE()                                                              \
        {   _Pragma("unroll")                                                    \
            for (int s = 0; s < 8; ++s) {                                        \
                int idx = tid + (s << 8);                                        \
                int kv = idx >> 5, dq = idx & 31;                                \
                int off = kv * DH + ((dq * 4) ^ ((kv & 7) << 3));                \
                uint2 u; u.x = pk2bf(kreg[s].x, kreg[s].y);                      \
                         u.y = pk2bf(kreg[s].z, kreg[s].w);                      \
                *(uint2*)&LK[off] = u;                                           \
            }                                                                    \
            _Pragma("unroll")                                                    \
            for (int t = 0; t < 4; ++t) {                                        \
                int idx = tid + (t << 8);                                        \
                int d = idx & 127, kvb = idx >> 7;                               \
                int off = d * KVC + ((kvb * 8) ^ ((d & 7) << 3));                \
                uint4 u; u.x = pk2bf(vreg[t][0], vreg[t][1]);                    \
                         u.y = pk2bf(vreg[t][2], vreg[t][3]);                    \
                         u.z = pk2bf(vreg[t][4], vreg[t][5]);                    \
                         u.w = pk2bf(vreg[t][6], vreg[t][7]);                    \
                *(uint4*)&VT[off] = u;                                           \
            }                                                                    \
        }

    ISSUE(kvaddr(ch0));
    WRITE();
    __syncthreads();

    unsigned short* Pw = &PL[wv][0];   // per-wave private P buffer, no barrier needed

    for (int ch = 0; ch < nch; ++ch) {
        if (ch + 1 < nch) ISSUE(kvaddr(ch0 + ch + 1));   // fly under this chunk's compute

        // ---- S^T = K * Q^T : st[n][kt][r] = S[kv=kt*16+g*4+r][q=n*16+q'] ----
        f32x4 st[2][4];
        #pragma unroll
        for (int n = 0; n < 2; ++n)
            #pragma unroll
            for (int kt = 0; kt < 4; ++kt) st[n][kt] = f32x4{0.f, 0.f, 0.f, 0.f};
        __builtin_amdgcn_s_setprio(1);
        #pragma unroll
        for (int c = 0; c < 4; ++c) {
            #pragma unroll
            for (int kt = 0; kt < 4; ++kt) {
                bf16x8 kf = *(const bf16x8*)((const char*)LK
                              + (kt*16 + q) * 256 + ((c * 64 + g * 16) ^ sw16));
                st[0][kt] = __builtin_amdgcn_mfma_f32_16x16x32_bf16(kf, qf[0][c], st[0][kt], 0, 0, 0);
                st[1][kt] = __builtin_amdgcn_mfma_f32_16x16x32_bf16(kf, qf[1][c], st[1][kt], 0, 0, 0);
            }
        }
        __builtin_amdgcn_s_setprio(0);

        // ---- online softmax (log2 domain), defer-max (T13) ----
        float cm[2];
        #pragma unroll
        for (int n = 0; n < 2; ++n) {
            float c0 = -INFINITY;
            #pragma unroll
            for (int kt = 0; kt < 4; ++kt)
                #pragma unroll
                for (int r = 0; r < 4; ++r) c0 = fmaxf(c0, st[n][kt][r]);
            c0 = fmaxf(c0, __shfl_xor(c0, 16));
            c0 = fmaxf(c0, __shfl_xor(c0, 32));
            cm[n] = c0;
        }
        if (!__all((cm[0] <= mrun[0] + DEFER_THR) && (cm[1] <= mrun[1] + DEFER_THR))) {
            #pragma unroll
            for (int n = 0; n < 2; ++n) {
                float mnew = fmaxf(mrun[n], cm[n]);
                float sc = exp2f(mrun[n] - mnew);
                lsum[n] *= sc;
                #pragma unroll
                for (int dt = 0; dt < 8; ++dt) o[n][dt] *= sc;
                mrun[n] = mnew;
            }
        }

        unsigned pk[2][4][2];
        #pragma unroll
        for (int n = 0; n < 2; ++n) {
            float ps = 0.f;
            #pragma unroll
            for (int kt = 0; kt < 4; ++kt) {
                float p0 = exp2f(st[n][kt][0] - mrun[n]);
                float p1 = exp2f(st[n][kt][1] - mrun[n]);
                float p2 = exp2f(st[n][kt][2] - mrun[n]);
                float p3 = exp2f(st[n][kt][3] - mrun[n]);
                ps += (p0 + p1) + (p2 + p3);
                pk[n][kt][0] = pk2bf(p0, p1);
                pk[n][kt][1] = pk2bf(p2, p3);
            }
            ps += __shfl_xor(ps, 16);
            ps += __shfl_xor(ps, 32);
            lsum[n] += ps;
        }

        // ---- P -> per-wave LDS [32 q][64 kv] bf16, 16B-granule swizzled ----
        #pragma unroll
        for (int n = 0; n < 2; ++n)
            #pragma unroll
            for (int kt = 0; kt < 4; ++kt) {
                int gran = ((kt * 2 + (g >> 1)) ^ (q & 7));
                int boff = (n * 16 + q) * 128 + gran * 16 + (g & 1) * 8;
                uint2 u; u.x = pk[n][kt][0]; u.y = pk[n][kt][1];
                *(uint2*)((char*)Pw + boff) = u;
            }
        bf16x8 pf[2][2];
        #pragma unroll
        for (int n = 0; n < 2; ++n)
            #pragma unroll
            for (int f = 0; f < 2; ++f) {
                int gran = ((f * 4 + g) ^ (q & 7));
                pf[n][f] = *(const bf16x8*)((const char*)Pw + (n * 16 + q) * 128 + gran * 16);
            }

        // ---- O^T += V^T * P^T : o[n][dt][r] = O[q=n*16+q'][d=dt*16+g*4+r] ----
        __builtin_amdgcn_s_setprio(1);
        #pragma unroll
        for (int f = 0; f < 2; ++f) {
            #pragma unroll
            for (int dt = 0; dt < 8; ++dt) {
                bf16x8 vf = *(const bf16x8*)((const char*)VT
                              + (dt*16 + q) * 128 + ((f * 64 + g * 16) ^ sw16));
                o[0][dt] = __builtin_amdgcn_mfma_f32_16x16x32_bf16(vf, pf[0][f], o[0][dt], 0, 0, 0);
                o[1][dt] = __builtin_amdgcn_mfma_f32_16x16x32_bf16(vf, pf[1][f], o[1][dt], 0, 0, 0);
            }
        }
        __builtin_amdgcn_s_setprio(0);

        if (ch + 1 < nch) {
            __syncthreads();       // all waves done reading LDS
            WRITE();               // vmcnt wait lands here, loads flew under compute
            __syncthreads();
        }
    }

    if constexpr (SPLIT) {
        float* opb = Opart + (size_t)pid * (QT * DH);
        #pragma unroll
        for (int n = 0; n < 2; ++n) {
            const int row = wv * 32 + n * 16 + q;
            float* op = opb + row * DH;
            #pragma unroll
            for (int dt = 0; dt < 8; ++dt) {
                float4 v;
                v.x = o[n][dt][0]; v.y = o[n][dt][1]; v.z = o[n][dt][2]; v.w = o[n][dt][3];
                *(float4*)(op + dt * 16 + g * 4) = v;
            }
            if (g == 0) {
                Ml[(size_t)pid * (QT * 2) + row * 2]     = mrun[n];
                Ml[(size_t)pid * (QT * 2) + row * 2 + 1] = lsum[n];
            }
        }
    } else {
        #pragma unroll
        for (int n = 0; n < 2; ++n) {
            const int qrow = qbase + wv * 32 + n * 16 + q;
            if (qrow >= SEQ) continue;
            const float inv = 1.f / (lsum[n] + 64.f * exp2f(-mrun[n]));
            float* op = Og + hoff + (size_t)qrow * DH;
            #pragma unroll
            for (int dt = 0; dt < 8; ++dt) {
                float4 v;
                v.x = o[n][dt][0] * inv; v.y = o[n][dt][1] * inv;
                v.z = o[n][dt][2] * inv; v.w = o[n][dt][3] * inv;
                *(float4*)(op + dt * 16 + g * 4) = v;
            }
        }
    }
    #undef ISSUE
    #undef WRITE
}

__global__ __launch_bounds__(256) void sta_merge(const float* __restrict__ Opart,
                                                 const float* __restrict__ Ml,
                                                 float* __restrict__ Og) {
    const int b = blockIdx.x;             // 0..335: original q-tile
    const int t = threadIdx.x;
    int head, qbase, S, pbase;
    if (b < NHEADS * NTT) {
        head = b / NTT; qbase = IMG_LEN + (b % NTT) * QT;
        S = TSPLIT; pbase = b * TSPLIT;
    } else {
        int tile = b - NHEADS * NTT;
        head = tile / NIT; qbase = (tile % NIT) * QT;
        S = ISPLIT; pbase = NTXTB + tile * ISPLIT;
    }
    const int row = t >> 1;               // 0..127
    const int c0  = (t & 1) * 64;
    if (qbase + row >= SEQ) return;       // text tile 2 tail

    float mv[TSPLIT], lv[TSPLIT], w[TSPLIT];
    float m = -INFINITY;
    for (int s = 0; s < S; ++s) {
        mv[s] = Ml[(size_t)(pbase + s) * (QT * 2) + row * 2];
        lv[s] = Ml[(size_t)(pbase + s) * (QT * 2) + row * 2 + 1];
        m = fmaxf(m, mv[s]);
    }
    float L = 64.f * exp2f(-m);           // 64 zero-pad keys (log2 domain)
    for (int s = 0; s < S; ++s) { w[s] = exp2f(mv[s] - m); L += w[s] * lv[s]; }
    const float inv = 1.f / L;

    float* op = Og + (size_t)head * SEQ * DH + (size_t)(qbase + row) * DH + c0;
    #pragma unroll
    for (int j = 0; j < 16; ++j) {
        float4 acc = make_float4(0.f, 0.f, 0.f, 0.f);
        for (int s = 0; s < S; ++s) {
            const float4 p = *(const float4*)(Opart + (size_t)(pbase + s) * (QT * DH)
                                              + row * DH + c0 + j * 4);
            acc.x += w[s] * p.x; acc.y += w[s] * p.y;
            acc.z += w[s] * p.z; acc.w += w[s] * p.w;
        }
        float4 v; v.x = acc.x * inv; v.y = acc.y * inv; v.z = acc.z * inv; v.w = acc.w * inv;
        *(float4*)(op + j * 4) = v;
    }
}

extern "C" void kernel_launch(void* const* d_in, const int* in_sizes, int n_in,
                              void* d_out, int out_size, void* d_ws, size_t ws_size,
                              hipStream_t stream) {
    const float* Qg = (const float*)d_in[0];
    const float* Kg = (const float*)d_in[1];
    const float* Vg = (const float*)d_in[2];
    float* Og = (float*)d_out;

    const size_t need = (WS_OP_FLOATS + WS_ML_FLOATS) * sizeof(float);
    if (ws_size >= need) {
        float* Opart = (float*)d_ws;
        float* Ml    = Opart + WS_OP_FLOATS;
        hipLaunchKernelGGL(sta_attn<true>, dim3(NPID), dim3(256), 0, stream,
                           Qg, Kg, Vg, Og, Opart, Ml);
        hipLaunchKernelGGL(sta_merge, dim3(NHEADS * (NTT + NIT)), dim3(256), 0, stream,
                           Opart, Ml, Og);
    } else {
        hipLaunchKernelGGL(sta_attn<false>, dim3(NHEADS * (NTT + NIT)), dim3(256), 0, stream,
                           Qg, Kg, Vg, Og, (float*)nullptr, (float*)nullptr);
    }
}

// Round 6
// 354.109 us; speedup vs baseline: 1.6265x; 1.6265x over previous
//
#include <hip/hip_runtime.h>

// ---- problem constants (from reference) ----
#define SEQ      10688      // IMG_LEN + TEXT_LEN
#define IMG_LEN  10368      // 18*24*24
#define TEXT_LEN 320
#define DH       128
#define NHEADS   4
#define SLAB     3456       // 6*24*24 tokens per time-slab
#define KVC      64         // kv chunk rows
#define QT       128        // q rows per block (4 waves x 32)
#define NIT      81         // image q-tiles per head (IMG_LEN/128; 27 per slab, exact)
#define NTT      3          // text q-tiles per head (last tile half-valid)
// (1/sqrt(128)) * log2(e): scores in log2 domain -> exp2f softmax
#define SCALEL2E 0.12751744518924593f
#define DEFER_THR 8.0f      // defer-max rescale threshold (T13)

// split-K config
#define TSPLIT   4          // text: 167 chunks -> 42/42/42/41
#define ISPLIT   2          // image: 59 chunks -> 30/29
#define NTXTB    (NHEADS * NTT * TSPLIT)              // 48
#define NIMGB    (NHEADS * NIT * ISPLIT)              // 648
#define NPID     (NTXTB + NIMGB)                      // 696
#define WS_OP_FLOATS   ((size_t)NPID * QT * DH)
#define WS_ML_FLOATS   ((size_t)NPID * QT * 2)

typedef __bf16 bf16x8 __attribute__((ext_vector_type(8)));
typedef float  f32x4  __attribute__((ext_vector_type(4)));

__device__ __forceinline__ unsigned pk2bf(float a, float b) {
    union { __bf16 h[2]; unsigned u; } t;
    t.h[0] = (__bf16)a; t.h[1] = (__bf16)b;
    return t.u;
}

// NOTE: NO min-waves arg! (256,4) capped VGPR at 64 (round 3), (256,2) capped
// at 128 (round 5) -- both spilled catastrophically (WRITE_SIZE 45->350+MB).
// This kernel needs ~230 VGPRs; unconstrained allocator -> zero spill,
// occupancy 2 blocks/CU (8 waves) which matches what we actually achieved.
template<bool SPLIT>
__global__ __launch_bounds__(256) void sta_attn(const float* __restrict__ Qg,
                                                const float* __restrict__ Kg,
                                                const float* __restrict__ Vg,
                                                float* __restrict__ Og,
                                                float* __restrict__ Opart,
                                                float* __restrict__ Ml) {
    // XOR-swizzled at 16B granule with row&7 key; no pads.
    __shared__ __align__(16) unsigned short LK[KVC * DH];     // K   [kv][d]   16KB
    __shared__ __align__(16) unsigned short VT[DH * KVC];     // V^T [d][kv]   16KB
    __shared__ __align__(16) unsigned short PL[4][32 * KVC];  // P   [q][kv] per wave 16KB

    const int tid  = threadIdx.x;
    const int lane = tid & 63;
    const int wv   = tid >> 6;
    const int q    = lane & 15;       // q-col within 16-wide MFMA tile
    const int g    = lane >> 4;       // lane group 0..3
    const int sw16 = (q & 7) << 4;    // 16B-granule swizzle key (bytes)

    int b = blockIdx.x;
    int head, qbase, nch, ch0, kvb0, pid = 0;
    bool isText;
    if constexpr (SPLIT) {
        if (b < NTXTB) {                       // text splits first (longest poles)
            int tb = b >> 2, s = b & 3;
            head = tb / NTT; qbase = IMG_LEN + (tb % NTT) * QT;
            isText = true; kvb0 = 0;
            ch0 = s * 42; nch = (s < 3) ? 42 : 41;
            pid = b;
        } else {
            int bb = b - NTXTB; int tile = bb >> 1, s = bb & 1;
            head = tile / NIT; qbase = (tile % NIT) * QT;
            isText = false; kvb0 = (qbase / SLAB) * SLAB;
            ch0 = s ? 30 : 0; nch = s ? 29 : 30;
            pid = NTXTB + bb;
        }
    } else {
        if (b < NHEADS * NTT) {
            head = b / NTT; qbase = IMG_LEN + (b % NTT) * QT;
            isText = true; ch0 = 0; nch = SEQ / KVC; kvb0 = 0;
        } else {
            int bb = b - NHEADS * NTT;
            head = bb / NIT; qbase = (bb % NIT) * QT;
            isText = false; ch0 = 0; nch = 54 + 5;
            kvb0 = (qbase / SLAB) * SLAB;
        }
    }

    const size_t hoff = (size_t)head * SEQ * DH;
    const float* Qh = Qg + hoff;
    const float* Kh = Kg + hoff;
    const float* Vh = Vg + hoff;

    // ---- Q fragments for 2 q-subtiles (B-operand layout), scale folded ----
    bf16x8 qf[2][4];
    #pragma unroll
    for (int n = 0; n < 2; ++n) {
        int qr = qbase + wv * 32 + n * 16 + q;
        if (qr > SEQ - 1) qr = SEQ - 1;            // text tile 2 tail: clamp (discarded at store)
        const float* qp = Qh + (size_t)qr * DH;
        #pragma unroll
        for (int c = 0; c < 4; ++c) {
            float4 a = *(const float4*)(qp + c * 32 + g * 8);
            float4 d = *(const float4*)(qp + c * 32 + g * 8 + 4);
            union { unsigned u[4]; bf16x8 v; } t;
            t.u[0] = pk2bf(a.x * SCALEL2E, a.y * SCALEL2E);
            t.u[1] = pk2bf(a.z * SCALEL2E, a.w * SCALEL2E);
            t.u[2] = pk2bf(d.x * SCALEL2E, d.y * SCALEL2E);
            t.u[3] = pk2bf(d.z * SCALEL2E, d.w * SCALEL2E);
            qf[n][c] = t.v;
        }
    }

    f32x4 o[2][8];
    #pragma unroll
    for (int n = 0; n < 2; ++n)
        #pragma unroll
        for (int dt = 0; dt < 8; ++dt) o[n][dt] = f32x4{0.f, 0.f, 0.f, 0.f};
    float mrun[2] = {-INFINITY, -INFINITY};
    float lsum[2] = {0.f, 0.f};

    float4 kreg[8];
    float  vreg[4][8];

    auto kvaddr = [&](int gch) -> int {
        return isText ? gch * KVC
                      : (gch < 54 ? kvb0 + gch * KVC : IMG_LEN + (gch - 54) * KVC);
    };

    #define ISSUE_K(KVBASE)                                                      \
        {   const int _kb = (KVBASE);                                            \
            _Pragma("unroll")                                                    \
            for (int s = 0; s < 8; ++s) {                                        \
                int idx = tid + (s << 8);                                        \
                int kv = idx >> 5, dq = idx & 31;                                \
                kreg[s] = *(const float4*)(Kh + (size_t)(_kb + kv) * DH + dq*4); \
            }                                                                    \
        }

    #define ISSUE_V(KVBASE)                                                      \
        {   const int _kb = (KVBASE);                                            \
            _Pragma("unroll")                                                    \
            for (int t = 0; t < 4; ++t) {                                        \
                int idx = tid + (t << 8);                                        \
                int d = idx & 127, kvb = idx >> 7;                               \
                const float* vp = Vh + (size_t)(_kb + kvb * 8) * DH + d;         \
                _Pragma("unroll")                                                \
                for (int j = 0; j < 8; ++j) vreg[t][j] = vp[j * DH];             \
            }                                                                    \
        }

    #define WRITE()                                                              \
        {   _Pragma("unroll")                                                    \
            for (int s = 0; s < 8; ++s) {                                        \
                int idx = tid + (s << 8);                                        \
                int kv = idx >> 5, dq = idx & 31;                                \
                int off = kv * DH + ((dq * 4) ^ ((kv & 7) << 3));                \
                uint2 u; u.x = pk2bf(kreg[s].x, kreg[s].y);                      \
                         u.y = pk2bf(kreg[s].z, kreg[s].w);                      \
                *(uint2*)&LK[off] = u;                                           \
            }                                                                    \
            _Pragma("unroll")                                                    \
            for (int t = 0; t < 4; ++t) {                                        \
                int idx = tid + (t << 8);                                        \
                int d = idx & 127, kvb = idx >> 7;                               \
                int off = d * KVC + ((kvb * 8) ^ ((d & 7) << 3));                \
                uint4 u; u.x = pk2bf(vreg[t][0], vreg[t][1]);                    \
                         u.y = pk2bf(vreg[t][2], vreg[t][3]);                    \
                         u.z = pk2bf(vreg[t][4], vreg[t][5]);                    \
                         u.w = pk2bf(vreg[t][6], vreg[t][7]);                    \
                *(uint4*)&VT[off] = u;                                           \
            }                                                                    \
        }

    ISSUE_K(kvaddr(ch0));
    ISSUE_V(kvaddr(ch0));
    WRITE();
    __syncthreads();

    unsigned short* Pw = &PL[wv][0];   // per-wave private P buffer, no barrier needed

    for (int ch = 0; ch < nch; ++ch) {
        // K loads for next chunk fly under QK^T + softmax (only 32 regs live)
        if (ch + 1 < nch) ISSUE_K(kvaddr(ch0 + ch + 1));

        // ---- S^T = K * Q^T : st[n][kt][r] = S[kv=kt*16+g*4+r][q=n*16+q'] ----
        f32x4 st[2][4];
        #pragma unroll
        for (int n = 0; n < 2; ++n)
            #pragma unroll
            for (int kt = 0; kt < 4; ++kt) st[n][kt] = f32x4{0.f, 0.f, 0.f, 0.f};
        __builtin_amdgcn_s_setprio(1);
        #pragma unroll
        for (int c = 0; c < 4; ++c) {
            #pragma unroll
            for (int kt = 0; kt < 4; ++kt) {
                bf16x8 kf = *(const bf16x8*)((const char*)LK
                              + (kt*16 + q) * 256 + ((c * 64 + g * 16) ^ sw16));
                st[0][kt] = __builtin_amdgcn_mfma_f32_16x16x32_bf16(kf, qf[0][c], st[0][kt], 0, 0, 0);
                st[1][kt] = __builtin_amdgcn_mfma_f32_16x16x32_bf16(kf, qf[1][c], st[1][kt], 0, 0, 0);
            }
        }
        __builtin_amdgcn_s_setprio(0);

        // ---- online softmax (log2 domain), defer-max (T13) ----
        float cm[2];
        #pragma unroll
        for (int n = 0; n < 2; ++n) {
            float c0 = -INFINITY;
            #pragma unroll
            for (int kt = 0; kt < 4; ++kt)
                #pragma unroll
                for (int r = 0; r < 4; ++r) c0 = fmaxf(c0, st[n][kt][r]);
            c0 = fmaxf(c0, __shfl_xor(c0, 16));
            c0 = fmaxf(c0, __shfl_xor(c0, 32));
            cm[n] = c0;
        }
        if (!__all((cm[0] <= mrun[0] + DEFER_THR) && (cm[1] <= mrun[1] + DEFER_THR))) {
            #pragma unroll
            for (int n = 0; n < 2; ++n) {
                float mnew = fmaxf(mrun[n], cm[n]);
                float sc = exp2f(mrun[n] - mnew);
                lsum[n] *= sc;
                #pragma unroll
                for (int dt = 0; dt < 8; ++dt) o[n][dt] *= sc;
                mrun[n] = mnew;
            }
        }

        unsigned pk[2][4][2];
        #pragma unroll
        for (int n = 0; n < 2; ++n) {
            float ps = 0.f;
            #pragma unroll
            for (int kt = 0; kt < 4; ++kt) {
                float p0 = exp2f(st[n][kt][0] - mrun[n]);
                float p1 = exp2f(st[n][kt][1] - mrun[n]);
                float p2 = exp2f(st[n][kt][2] - mrun[n]);
                float p3 = exp2f(st[n][kt][3] - mrun[n]);
                ps += (p0 + p1) + (p2 + p3);
                pk[n][kt][0] = pk2bf(p0, p1);
                pk[n][kt][1] = pk2bf(p2, p3);
            }
            ps += __shfl_xor(ps, 16);
            ps += __shfl_xor(ps, 32);
            lsum[n] += ps;
        }

        // ---- P -> per-wave LDS [32 q][64 kv] bf16, 16B-granule swizzled ----
        #pragma unroll
        for (int n = 0; n < 2; ++n)
            #pragma unroll
            for (int kt = 0; kt < 4; ++kt) {
                int gran = ((kt * 2 + (g >> 1)) ^ (q & 7));
                int boff = (n * 16 + q) * 128 + gran * 16 + (g & 1) * 8;
                uint2 u; u.x = pk[n][kt][0]; u.y = pk[n][kt][1];
                *(uint2*)((char*)Pw + boff) = u;
            }

        // V loads for next chunk fly under P-roundtrip + PV + barrier
        if (ch + 1 < nch) ISSUE_V(kvaddr(ch0 + ch + 1));

        bf16x8 pf[2][2];
        #pragma unroll
        for (int n = 0; n < 2; ++n)
            #pragma unroll
            for (int f = 0; f < 2; ++f) {
                int gran = ((f * 4 + g) ^ (q & 7));
                pf[n][f] = *(const bf16x8*)((const char*)Pw + (n * 16 + q) * 128 + gran * 16);
            }

        // ---- O^T += V^T * P^T : o[n][dt][r] = O[q=n*16+q'][d=dt*16+g*4+r] ----
        __builtin_amdgcn_s_setprio(1);
        #pragma unroll
        for (int f = 0; f < 2; ++f) {
            #pragma unroll
            for (int dt = 0; dt < 8; ++dt) {
                bf16x8 vf = *(const bf16x8*)((const char*)VT
                              + (dt*16 + q) * 128 + ((f * 64 + g * 16) ^ sw16));
                o[0][dt] = __builtin_amdgcn_mfma_f32_16x16x32_bf16(vf, pf[0][f], o[0][dt], 0, 0, 0);
                o[1][dt] = __builtin_amdgcn_mfma_f32_16x16x32_bf16(vf, pf[1][f], o[1][dt], 0, 0, 0);
            }
        }
        __builtin_amdgcn_s_setprio(0);

        if (ch + 1 < nch) {
            __syncthreads();       // all waves done reading LDS
            WRITE();               // vmcnt wait lands here, loads flew under compute
            __syncthreads();
        }
    }

    if constexpr (SPLIT) {
        float* opb = Opart + (size_t)pid * (QT * DH);
        #pragma unroll
        for (int n = 0; n < 2; ++n) {
            const int row = wv * 32 + n * 16 + q;
            float* op = opb + row * DH;
            #pragma unroll
            for (int dt = 0; dt < 8; ++dt) {
                float4 v;
                v.x = o[n][dt][0]; v.y = o[n][dt][1]; v.z = o[n][dt][2]; v.w = o[n][dt][3];
                *(float4*)(op + dt * 16 + g * 4) = v;
            }
            if (g == 0) {
                Ml[(size_t)pid * (QT * 2) + row * 2]     = mrun[n];
                Ml[(size_t)pid * (QT * 2) + row * 2 + 1] = lsum[n];
            }
        }
    } else {
        #pragma unroll
        for (int n = 0; n < 2; ++n) {
            const int qrow = qbase + wv * 32 + n * 16 + q;
            if (qrow >= SEQ) continue;
            const float inv = 1.f / (lsum[n] + 64.f * exp2f(-mrun[n]));
            float* op = Og + hoff + (size_t)qrow * DH;
            #pragma unroll
            for (int dt = 0; dt < 8; ++dt) {
                float4 v;
                v.x = o[n][dt][0] * inv; v.y = o[n][dt][1] * inv;
                v.z = o[n][dt][2] * inv; v.w = o[n][dt][3] * inv;
                *(float4*)(op + dt * 16 + g * 4) = v;
            }
        }
    }
    #undef ISSUE_K
    #undef ISSUE_V
    #undef WRITE
}

__global__ __launch_bounds__(256) void sta_merge(const float* __restrict__ Opart,
                                                 const float* __restrict__ Ml,
                                                 float* __restrict__ Og) {
    const int b = blockIdx.x;             // 0..335: original q-tile
    const int t = threadIdx.x;
    int head, qbase, S, pbase;
    if (b < NHEADS * NTT) {
        head = b / NTT; qbase = IMG_LEN + (b % NTT) * QT;
        S = TSPLIT; pbase = b * TSPLIT;
    } else {
        int tile = b - NHEADS * NTT;
        head = tile / NIT; qbase = (tile % NIT) * QT;
        S = ISPLIT; pbase = NTXTB + tile * ISPLIT;
    }
    const int row = t >> 1;               // 0..127
    const int c0  = (t & 1) * 64;
    if (qbase + row >= SEQ) return;       // text tile 2 tail

    float mv[TSPLIT], lv[TSPLIT], w[TSPLIT];
    float m = -INFINITY;
    for (int s = 0; s < S; ++s) {
        mv[s] = Ml[(size_t)(pbase + s) * (QT * 2) + row * 2];
        lv[s] = Ml[(size_t)(pbase + s) * (QT * 2) + row * 2 + 1];
        m = fmaxf(m, mv[s]);
    }
    float L = 64.f * exp2f(-m);           // 64 zero-pad keys (log2 domain)
    for (int s = 0; s < S; ++s) { w[s] = exp2f(mv[s] - m); L += w[s] * lv[s]; }
    const float inv = 1.f / L;

    float* op = Og + (size_t)head * SEQ * DH + (size_t)(qbase + row) * DH + c0;
    #pragma unroll
    for (int j = 0; j < 16; ++j) {
        float4 acc = make_float4(0.f, 0.f, 0.f, 0.f);
        for (int s = 0; s < S; ++s) {
            const float4 p = *(const float4*)(Opart + (size_t)(pbase + s) * (QT * DH)
                                              + row * DH + c0 + j * 4);
            acc.x += w[s] * p.x; acc.y += w[s] * p.y;
            acc.z += w[s] * p.z; acc.w += w[s] * p.w;
        }
        float4 v; v.x = acc.x * inv; v.y = acc.y * inv; v.z = acc.z * inv; v.w = acc.w * inv;
        *(float4*)(op + j * 4) = v;
    }
}

extern "C" void kernel_launch(void* const* d_in, const int* in_sizes, int n_in,
                              void* d_out, int out_size, void* d_ws, size_t ws_size,
                              hipStream_t stream) {
    const float* Qg = (const float*)d_in[0];
    const float* Kg = (const float*)d_in[1];
    const float* Vg = (const float*)d_in[2];
    float* Og = (float*)d_out;

    const size_t need = (WS_OP_FLOATS + WS_ML_FLOATS) * sizeof(float);
    if (ws_size >= need) {
        float* Opart = (float*)d_ws;
        float* Ml    = Opart + WS_OP_FLOATS;
        hipLaunchKernelGGL(sta_attn<true>, dim3(NPID), dim3(256), 0, stream,
                           Qg, Kg, Vg, Og, Opart, Ml);
        hipLaunchKernelGGL(sta_merge, dim3(NHEADS * (NTT + NIT)), dim3(256), 0, stream,
                           Opart, Ml, Og);
    } else {
        hipLaunchKernelGGL(sta_attn<false>, dim3(NHEADS * (NTT + NIT)), dim3(256), 0, stream,
                           Qg, Kg, Vg, Og, (float*)nullptr, (float*)nullptr);
    }
}

// Round 7
// 256.442 us; speedup vs baseline: 2.2459x; 1.3809x over previous
//
#include <hip/hip_runtime.h>

// ---- problem constants (from reference) ----
#define SEQ      10688      // IMG_LEN + TEXT_LEN
#define IMG_LEN  10368      // 18*24*24
#define TEXT_LEN 320
#define DH       128
#define NHEADS   4
#define SLAB     3456       // 6*24*24 tokens per time-slab
#define KVC      64         // kv chunk rows
#define QT       128        // q rows per block (4 waves x 32)
#define NIT      81         // image q-tiles per head
#define NTT      3          // text q-tiles per head (last tile half-valid)
#define SCALEL2E 0.12751744518924593f   // (1/sqrt(128)) * log2(e)
#define DEFER_THR 8.0f      // defer-max rescale threshold (T13)

// split-K config
#define TSPLIT   4          // text: 167 chunks -> 42/42/42/41
#define ISPLIT   2          // image: 59 chunks -> 30/29
#define NTXTB    (NHEADS * NTT * TSPLIT)              // 48
#define NIMGB    (NHEADS * NIT * ISPLIT)              // 648
#define NPID     (NTXTB + NIMGB)                      // 696
#define WS_OP_FLOATS   ((size_t)NPID * QT * DH)
#define WS_ML_FLOATS   ((size_t)NPID * QT * 2)

typedef __bf16 bf16x8 __attribute__((ext_vector_type(8)));
typedef __bf16 bf16x4 __attribute__((ext_vector_type(4)));
typedef float  f32x4  __attribute__((ext_vector_type(4)));

__device__ __forceinline__ unsigned pk2bf(float a, float b) {
    union { __bf16 h[2]; unsigned u; } t;
    t.h[0] = (__bf16)a; t.h[1] = (__bf16)b;
    return t.u;
}

// NOTE: NO min-waves clamp! (256,4)->64 VGPR and (256,2)->128 VGPR both caused
// catastrophic scratch spills (rounds 3/5). Unconstrained allocator, target
// <=170 VGPR for 3 waves/SIMD (12 waves/CU, 3 blocks/CU with 32KB LDS).
template<bool SPLIT>
__global__ __launch_bounds__(256) void sta_attn(const float* __restrict__ Qg,
                                                const float* __restrict__ Kg,
                                                const float* __restrict__ Vg,
                                                float* __restrict__ Og,
                                                float* __restrict__ Opart,
                                                float* __restrict__ Ml) {
    // K: [kv][d] bf16, 8-elem-granule XOR swizzle key (kv&7).
    // V^T: [d][kv] bf16, 8-elem-granule XOR swizzle key ((d>>1)&7).
    __shared__ __align__(16) unsigned short LK[KVC * DH];     // 16KB
    __shared__ __align__(16) unsigned short VT[DH * KVC];     // 16KB

    const int tid  = threadIdx.x;
    const int lane = tid & 63;
    const int wv   = tid >> 6;
    const int q    = lane & 15;       // MFMA col position (q for QK/PV outputs)
    const int g    = lane >> 4;       // lane group 0..3
    const int sw16 = (q & 7) << 4;    // K-read swizzle key (bytes)
    const int qk2  = q >> 1;          // V-read swizzle key
    const int gh   = g >> 1;
    const int gb   = (g & 1) * 8;     // byte sub-offset within V granule
    const int d2   = tid & 63;        // V staging: d-pair index
    const int kvb  = tid >> 6;        // V staging: kv block of 16

    int b = blockIdx.x;
    int head, qbase, nch, ch0, kvb0, pid = 0;
    bool isText;
    if constexpr (SPLIT) {
        if (b < NTXTB) {                       // text splits first (longest poles)
            int tb = b >> 2, s = b & 3;
            head = tb / NTT; qbase = IMG_LEN + (tb % NTT) * QT;
            isText = true; kvb0 = 0;
            ch0 = s * 42; nch = (s < 3) ? 42 : 41;
            pid = b;
        } else {
            int bb = b - NTXTB; int tile = bb >> 1, s = bb & 1;
            head = tile / NIT; qbase = (tile % NIT) * QT;
            isText = false; kvb0 = (qbase / SLAB) * SLAB;
            ch0 = s ? 30 : 0; nch = s ? 29 : 30;
            pid = NTXTB + bb;
        }
    } else {
        if (b < NHEADS * NTT) {
            head = b / NTT; qbase = IMG_LEN + (b % NTT) * QT;
            isText = true; ch0 = 0; nch = SEQ / KVC; kvb0 = 0;
        } else {
            int bb = b - NHEADS * NTT;
            head = bb / NIT; qbase = (bb % NIT) * QT;
            isText = false; ch0 = 0; nch = 54 + 5;
            kvb0 = (qbase / SLAB) * SLAB;
        }
    }

    const size_t hoff = (size_t)head * SEQ * DH;
    const float* Qh = Qg + hoff;
    const float* Kh = Kg + hoff;
    const float* Vh = Vg + hoff;

    // ---- Q fragments for 2 q-subtiles (B-operand layout), scale folded ----
    bf16x8 qf[2][4];
    #pragma unroll
    for (int n = 0; n < 2; ++n) {
        int qr = qbase + wv * 32 + n * 16 + q;
        if (qr > SEQ - 1) qr = SEQ - 1;        // text tail: clamp (discarded at store)
        const float* qp = Qh + (size_t)qr * DH;
        #pragma unroll
        for (int c = 0; c < 4; ++c) {
            float4 a = *(const float4*)(qp + c * 32 + g * 8);
            float4 d = *(const float4*)(qp + c * 32 + g * 8 + 4);
            union { unsigned u[4]; bf16x8 v; } t;
            t.u[0] = pk2bf(a.x * SCALEL2E, a.y * SCALEL2E);
            t.u[1] = pk2bf(a.z * SCALEL2E, a.w * SCALEL2E);
            t.u[2] = pk2bf(d.x * SCALEL2E, d.y * SCALEL2E);
            t.u[3] = pk2bf(d.z * SCALEL2E, d.w * SCALEL2E);
            qf[n][c] = t.v;
        }
    }

    f32x4 o[2][8];
    #pragma unroll
    for (int n = 0; n < 2; ++n)
        #pragma unroll
        for (int dt = 0; dt < 8; ++dt) o[n][dt] = f32x4{0.f, 0.f, 0.f, 0.f};
    float mrun[2] = {-INFINITY, -INFINITY};
    float lsum[2] = {0.f, 0.f};

    auto kvaddr = [&](int gch) -> int {
        return isText ? gch * KVC
                      : (gch < 54 ? kvb0 + gch * KVC : IMG_LEN + (gch - 54) * KVC);
    };

    // Inline staging: no persistent staging registers (transients only).
    // K: 8 float4/thread; V: 16 float2/thread (d pair 2*d2, 2*d2+1; kv kvb*16+j).
    #define STAGE(KB)                                                            \
        {   const int _kb = (KB);                                                \
            float4 kf4[8];                                                       \
            _Pragma("unroll")                                                    \
            for (int s = 0; s < 8; ++s) {                                        \
                int idx = tid + (s << 8);                                        \
                kf4[s] = *(const float4*)(Kh + (size_t)(_kb + (idx >> 5)) * DH   \
                                          + (idx & 31) * 4);                     \
            }                                                                    \
            const float* vpp = Vh + (size_t)(_kb + kvb * 16) * DH + d2 * 2;      \
            float2 va[8];                                                        \
            _Pragma("unroll")                                                    \
            for (int j = 0; j < 8; ++j) va[j] = *(const float2*)(vpp + j * DH);  \
            _Pragma("unroll")                                                    \
            for (int s = 0; s < 8; ++s) {                                        \
                int idx = tid + (s << 8);                                        \
                int kv = idx >> 5, dq = idx & 31;                                \
                uint2 u; u.x = pk2bf(kf4[s].x, kf4[s].y);                        \
                         u.y = pk2bf(kf4[s].z, kf4[s].w);                        \
                *(uint2*)&LK[kv * DH + ((dq * 4) ^ ((kv & 7) << 3))] = u;        \
            }                                                                    \
            float2 vb[8];                                                        \
            _Pragma("unroll")                                                    \
            for (int j = 0; j < 8; ++j) vb[j] = *(const float2*)(vpp + (8 + j) * DH); \
            const int g0 = ((kvb * 2 + 0) ^ (d2 & 7)) * 8;                       \
            const int g1 = ((kvb * 2 + 1) ^ (d2 & 7)) * 8;                       \
            _Pragma("unroll")                                                    \
            for (int h = 0; h < 2; ++h) {                                        \
                const int d = d2 * 2 + h;                                        \
                uint4 u0, u1;                                                    \
                u0.x = pk2bf(h ? va[0].y : va[0].x, h ? va[1].y : va[1].x);      \
                u0.y = pk2bf(h ? va[2].y : va[2].x, h ? va[3].y : va[3].x);      \
                u0.z = pk2bf(h ? va[4].y : va[4].x, h ? va[5].y : va[5].x);      \
                u0.w = pk2bf(h ? va[6].y : va[6].x, h ? va[7].y : va[7].x);      \
                u1.x = pk2bf(h ? vb[0].y : vb[0].x, h ? vb[1].y : vb[1].x);      \
                u1.y = pk2bf(h ? vb[2].y : vb[2].x, h ? vb[3].y : vb[3].x);      \
                u1.z = pk2bf(h ? vb[4].y : vb[4].x, h ? vb[5].y : vb[5].x);      \
                u1.w = pk2bf(h ? vb[6].y : vb[6].x, h ? vb[7].y : vb[7].x);      \
                *(uint4*)&VT[d * KVC + g0] = u0;                                 \
                *(uint4*)&VT[d * KVC + g1] = u1;                                 \
            }                                                                    \
        }

    STAGE(kvaddr(ch0));
    __syncthreads();

    for (int ch = 0; ch < nch; ++ch) {
        // ---- S^T = K * Q^T : st[n][kt][r] = S[kv=kt*16+g*4+r][q=n*16+q'] ----
        f32x4 st[2][4];
        #pragma unroll
        for (int n = 0; n < 2; ++n)
            #pragma unroll
            for (int kt = 0; kt < 4; ++kt) st[n][kt] = f32x4{0.f, 0.f, 0.f, 0.f};
        __builtin_amdgcn_s_setprio(1);
        #pragma unroll
        for (int c = 0; c < 4; ++c) {
            #pragma unroll
            for (int kt = 0; kt < 4; ++kt) {
                bf16x8 kf = *(const bf16x8*)((const char*)LK
                              + (kt*16 + q) * 256 + ((c * 64 + g * 16) ^ sw16));
                st[0][kt] = __builtin_amdgcn_mfma_f32_16x16x32_bf16(kf, qf[0][c], st[0][kt], 0, 0, 0);
                st[1][kt] = __builtin_amdgcn_mfma_f32_16x16x32_bf16(kf, qf[1][c], st[1][kt], 0, 0, 0);
            }
        }
        __builtin_amdgcn_s_setprio(0);

        // ---- online softmax (log2 domain), defer-max ----
        float cm[2];
        #pragma unroll
        for (int n = 0; n < 2; ++n) {
            float c0 = -INFINITY;
            #pragma unroll
            for (int kt = 0; kt < 4; ++kt)
                #pragma unroll
                for (int r = 0; r < 4; ++r) c0 = fmaxf(c0, st[n][kt][r]);
            c0 = fmaxf(c0, __shfl_xor(c0, 16));
            c0 = fmaxf(c0, __shfl_xor(c0, 32));
            cm[n] = c0;
        }
        if (!__all((cm[0] <= mrun[0] + DEFER_THR) && (cm[1] <= mrun[1] + DEFER_THR))) {
            #pragma unroll
            for (int n = 0; n < 2; ++n) {
                float mnew = fmaxf(mrun[n], cm[n]);
                float sc = exp2f(mrun[n] - mnew);
                lsum[n] *= sc;
                #pragma unroll
                for (int dt = 0; dt < 8; ++dt) o[n][dt] *= sc;
                mrun[n] = mnew;
            }
        }

        // P in bf16: the K=16 B-fragment (k=g*4+j, col=q) IS the st layout ->
        // feeds PV directly, no LDS/shuffle redistribution.
        bf16x4 pkv[2][4];
        #pragma unroll
        for (int n = 0; n < 2; ++n) {
            float ps = 0.f;
            #pragma unroll
            for (int kt = 0; kt < 4; ++kt) {
                float p0 = exp2f(st[n][kt][0] - mrun[n]);
                float p1 = exp2f(st[n][kt][1] - mrun[n]);
                float p2 = exp2f(st[n][kt][2] - mrun[n]);
                float p3 = exp2f(st[n][kt][3] - mrun[n]);
                ps += (p0 + p1) + (p2 + p3);
                union { unsigned u[2]; bf16x4 v; } t;
                t.u[0] = pk2bf(p0, p1);
                t.u[1] = pk2bf(p2, p3);
                pkv[n][kt] = t.v;
            }
            ps += __shfl_xor(ps, 16);
            ps += __shfl_xor(ps, 32);
            lsum[n] += ps;
        }

        // ---- O^T += V^T * P^T via K=16 MFMA, A=V^T from LDS (b64), B=pkv regs ----
        __builtin_amdgcn_s_setprio(1);
        #pragma unroll
        for (int kt = 0; kt < 4; ++kt) {
            bf16x4 vfr[8];
            #pragma unroll
            for (int dt = 0; dt < 8; ++dt) {
                const int d = dt * 16 + q;
                vfr[dt] = *(const bf16x4*)((const char*)VT
                            + d * 128 + (((kt * 2 + gh) ^ qk2) << 4) + gb);
            }
            #pragma unroll
            for (int dt = 0; dt < 8; ++dt) {
                asm("v_mfma_f32_16x16x16_bf16 %0, %1, %2, %0"
                    : "+v"(o[0][dt]) : "v"(vfr[dt]), "v"(pkv[0][kt]));
                asm("v_mfma_f32_16x16x16_bf16 %0, %1, %2, %0"
                    : "+v"(o[1][dt]) : "v"(vfr[dt]), "v"(pkv[1][kt]));
            }
        }
        __builtin_amdgcn_s_setprio(0);

        if (ch + 1 < nch) {
            __syncthreads();           // all waves done reading LDS
            STAGE(kvaddr(ch0 + ch + 1));
            __syncthreads();
        }
    }

    // hazard insurance: asm MFMA writes o[], epilogue VALU reads it soon after
    asm volatile("s_nop 7\n\ts_nop 7");

    if constexpr (SPLIT) {
        float* opb = Opart + (size_t)pid * (QT * DH);
        #pragma unroll
        for (int n = 0; n < 2; ++n) {
            const int row = wv * 32 + n * 16 + q;
            float* op = opb + row * DH;
            #pragma unroll
            for (int dt = 0; dt < 8; ++dt) {
                float4 v;
                v.x = o[n][dt][0]; v.y = o[n][dt][1]; v.z = o[n][dt][2]; v.w = o[n][dt][3];
                *(float4*)(op + dt * 16 + g * 4) = v;
            }
            if (g == 0) {
                Ml[(size_t)pid * (QT * 2) + row * 2]     = mrun[n];
                Ml[(size_t)pid * (QT * 2) + row * 2 + 1] = lsum[n];
            }
        }
    } else {
        #pragma unroll
        for (int n = 0; n < 2; ++n) {
            const int qrow = qbase + wv * 32 + n * 16 + q;
            if (qrow >= SEQ) continue;
            const float inv = 1.f / (lsum[n] + 64.f * exp2f(-mrun[n]));
            float* op = Og + hoff + (size_t)qrow * DH;
            #pragma unroll
            for (int dt = 0; dt < 8; ++dt) {
                float4 v;
                v.x = o[n][dt][0] * inv; v.y = o[n][dt][1] * inv;
                v.z = o[n][dt][2] * inv; v.w = o[n][dt][3] * inv;
                *(float4*)(op + dt * 16 + g * 4) = v;
            }
        }
    }
    #undef STAGE
}

__global__ __launch_bounds__(256) void sta_merge(const float* __restrict__ Opart,
                                                 const float* __restrict__ Ml,
                                                 float* __restrict__ Og) {
    const int b = blockIdx.x;             // original q-tile
    const int t = threadIdx.x;
    int head, qbase, S, pbase;
    if (b < NHEADS * NTT) {
        head = b / NTT; qbase = IMG_LEN + (b % NTT) * QT;
        S = TSPLIT; pbase = b * TSPLIT;
    } else {
        int tile = b - NHEADS * NTT;
        head = tile / NIT; qbase = (tile % NIT) * QT;
        S = ISPLIT; pbase = NTXTB + tile * ISPLIT;
    }
    const int row = t >> 1;               // 0..127
    const int c0  = (t & 1) * 64;
    if (qbase + row >= SEQ) return;       // text tail

    float mv[TSPLIT], lv[TSPLIT], w[TSPLIT];
    float m = -INFINITY;
    for (int s = 0; s < S; ++s) {
        mv[s] = Ml[(size_t)(pbase + s) * (QT * 2) + row * 2];
        lv[s] = Ml[(size_t)(pbase + s) * (QT * 2) + row * 2 + 1];
        m = fmaxf(m, mv[s]);
    }
    float L = 64.f * exp2f(-m);           // 64 zero-pad keys (log2 domain)
    for (int s = 0; s < S; ++s) { w[s] = exp2f(mv[s] - m); L += w[s] * lv[s]; }
    const float inv = 1.f / L;

    float* op = Og + (size_t)head * SEQ * DH + (size_t)(qbase + row) * DH + c0;
    #pragma unroll
    for (int j = 0; j < 16; ++j) {
        float4 acc = make_float4(0.f, 0.f, 0.f, 0.f);
        for (int s = 0; s < S; ++s) {
            const float4 p = *(const float4*)(Opart + (size_t)(pbase + s) * (QT * DH)
                                              + row * DH + c0 + j * 4);
            acc.x += w[s] * p.x; acc.y += w[s] * p.y;
            acc.z += w[s] * p.z; acc.w += w[s] * p.w;
        }
        float4 v; v.x = acc.x * inv; v.y = acc.y * inv; v.z = acc.z * inv; v.w = acc.w * inv;
        *(float4*)(op + j * 4) = v;
    }
}

extern "C" void kernel_launch(void* const* d_in, const int* in_sizes, int n_in,
                              void* d_out, int out_size, void* d_ws, size_t ws_size,
                              hipStream_t stream) {
    const float* Qg = (const float*)d_in[0];
    const float* Kg = (const float*)d_in[1];
    const float* Vg = (const float*)d_in[2];
    float* Og = (float*)d_out;

    const size_t need = (WS_OP_FLOATS + WS_ML_FLOATS) * sizeof(float);
    if (ws_size >= need) {
        float* Opart = (float*)d_ws;
        float* Ml    = Opart + WS_OP_FLOATS;
        hipLaunchKernelGGL(sta_attn<true>, dim3(NPID), dim3(256), 0, stream,
                           Qg, Kg, Vg, Og, Opart, Ml);
        hipLaunchKernelGGL(sta_merge, dim3(NHEADS * (NTT + NIT)), dim3(256), 0, stream,
                           Opart, Ml, Og);
    } else {
        hipLaunchKernelGGL(sta_attn<false>, dim3(NHEADS * (NTT + NIT)), dim3(256), 0, stream,
                           Qg, Kg, Vg, Og, (float*)nullptr, (float*)nullptr);
    }
}